// Round 1
// baseline (1221.327 us; speedup 1.0000x reference)
//
#include <hip/hip_runtime.h>
#include <math.h>

#define NN 200000
#define NE 200000
#define XBD 272  // other_mem(128) + edge_feat(128) + te(16)

__device__ __forceinline__ float sigm(float x) { return 1.0f / (1.0f + expf(-x)); }

// -------- phase 1: last_pos via atomicMax (== segment_max of positions) --------
__global__ void k_scatter(const int* __restrict__ src, const int* __restrict__ dst,
                          int* __restrict__ last_pos) {
    int i = blockIdx.x * blockDim.x + threadIdx.x;
    if (i < NE) {
        atomicMax(&last_pos[src[i]], i);
    } else if (i < 2 * NE) {
        atomicMax(&last_pos[dst[i - NE]], i);
    }
}

// -------- transpose W_ih / W_hh so GRU k-loops get coalesced float4 loads --------
__global__ void k_transpose(const float* __restrict__ Wih, const float* __restrict__ Whh,
                            float* __restrict__ WihT, float* __restrict__ WhhT) {
    int i = blockIdx.x * blockDim.x + threadIdx.x;
    if (i >= 384 * 128) return;
    int r = i >> 7, k = i & 127;
    WihT[k * 384 + r] = Wih[i];
    WhhT[k * 384 + r] = Whh[i];
}

// -------- compact present nodes (order nondeterministic; per-node result isn't) --------
__global__ void k_compact(const int* __restrict__ last_pos, int* __restrict__ plist,
                          int* __restrict__ cnt) {
    int n = blockIdx.x * blockDim.x + threadIdx.x;
    if (n < NN && last_pos[n] >= 0) {
        int idx = atomicAdd(cnt, 1);
        plist[idx] = n;
    }
}

// -------- absent nodes: out = memory --------
__global__ void k_copy_absent(const float* __restrict__ mem, const int* __restrict__ last_pos,
                              float* __restrict__ out) {
    int t = blockIdx.x * blockDim.x + threadIdx.x;
    int node = t >> 5;
    if (node >= NN) return;
    if (last_pos[node] < 0) {
        int c = (t & 31) * 4;
        *(float4*)&out[node * 128 + c] = *(const float4*)&mem[node * 128 + c];
    }
}

// -------- main: per present node, message MLP + GRU, fp32 --------
__global__ __launch_bounds__(256)
void k_main(const int* __restrict__ plist, const int* __restrict__ cnt_p,
            const int* __restrict__ last_pos,
            const int* __restrict__ src, const int* __restrict__ dst,
            const float* __restrict__ ef, const float* __restrict__ ts,
            const float* __restrict__ mem, const float* __restrict__ lut,
            const float* __restrict__ tw, const float* __restrict__ tphi,
            const float* __restrict__ W1, const float* __restrict__ b1,
            const float* __restrict__ W2, const float* __restrict__ b2,
            const float* __restrict__ WihT, const float* __restrict__ WhhT,
            const float* __restrict__ bih, const float* __restrict__ bhh,
            float* __restrict__ out)
{
    __shared__ float XA[32 * 128];   // mem[n] rows (kept alive for GRU h)
    __shared__ float XB[32 * XBD];   // [mem[other] | ef | te]; reused as H(0..4095) + MSG(4096..8191)
    __shared__ int   snode[32];

    const int cnt  = *cnt_p;
    const int base = blockIdx.x * 32;
    if (base >= cnt) return;
    const int nt   = min(32, cnt - base);
    const int tid  = threadIdx.x;
    const int lane = tid & 63;
    const int wv   = tid >> 6;

    // ---- stage X: one wave per node ----
    for (int i = wv; i < nt; i += 4) {
        int n = plist[base + i];
        if (lane == 0) snode[i] = n;
        int p = last_pos[n];
        int e, other;
        if (p < NE) { e = p;      other = dst[e]; }   // n is src of event e
        else        { e = p - NE; other = src[e]; }   // n is dst of event e
        float dt = ts[e] - lut[n];
        XA[i * 128 + lane]       = mem[n * 128 + lane];
        XA[i * 128 + 64 + lane]  = mem[n * 128 + 64 + lane];
        XB[i * XBD + lane]       = mem[other * 128 + lane];
        XB[i * XBD + 64 + lane]  = mem[other * 128 + 64 + lane];
        XB[i * XBD + 128 + lane] = ef[e * 128 + lane];
        XB[i * XBD + 192 + lane] = ef[e * 128 + 64 + lane];
        if (lane < 16) {
            float wt = fmaf(dt, tw[lane], tphi[lane]);
            XB[i * XBD + 256 + lane] = (lane == 0) ? wt : sinf(wt);
        }
    }
    __syncthreads();

    const int cg = tid & 31;   // 32 channel groups of 4
    const int ng = tid >> 5;   // 8 node groups of 4
    const int j0 = cg * 4;
    const int i0 = ng * 4;

    float acc[4][4];

    // ---- layer 1: h1 = relu(x @ W1 + b1), x = [XA | XB] ----
    #pragma unroll
    for (int a = 0; a < 4; ++a)
        #pragma unroll
        for (int b = 0; b < 4; ++b) acc[a][b] = 0.0f;

    for (int k = 0; k < 128; ++k) {
        const float4 w = *(const float4*)&W1[k * 128 + j0];
        #pragma unroll
        for (int ii = 0; ii < 4; ++ii) {
            float x = XA[(i0 + ii) * 128 + k];
            acc[ii][0] = fmaf(x, w.x, acc[ii][0]);
            acc[ii][1] = fmaf(x, w.y, acc[ii][1]);
            acc[ii][2] = fmaf(x, w.z, acc[ii][2]);
            acc[ii][3] = fmaf(x, w.w, acc[ii][3]);
        }
    }
    for (int k = 0; k < XBD; ++k) {
        const float4 w = *(const float4*)&W1[(128 + k) * 128 + j0];
        #pragma unroll
        for (int ii = 0; ii < 4; ++ii) {
            float x = XB[(i0 + ii) * XBD + k];
            acc[ii][0] = fmaf(x, w.x, acc[ii][0]);
            acc[ii][1] = fmaf(x, w.y, acc[ii][1]);
            acc[ii][2] = fmaf(x, w.z, acc[ii][2]);
            acc[ii][3] = fmaf(x, w.w, acc[ii][3]);
        }
    }
    const float4 bb1 = *(const float4*)&b1[j0];
    __syncthreads();   // everyone done reading XB; safe to overwrite with H

    float* __restrict__ H = XB;
    #pragma unroll
    for (int ii = 0; ii < 4; ++ii) {
        float4 h;
        h.x = fmaxf(acc[ii][0] + bb1.x, 0.0f);
        h.y = fmaxf(acc[ii][1] + bb1.y, 0.0f);
        h.z = fmaxf(acc[ii][2] + bb1.z, 0.0f);
        h.w = fmaxf(acc[ii][3] + bb1.w, 0.0f);
        *(float4*)&H[(i0 + ii) * 128 + j0] = h;
    }
    __syncthreads();

    // ---- layer 2: msg = h1 @ W2 + b2 ----
    #pragma unroll
    for (int a = 0; a < 4; ++a)
        #pragma unroll
        for (int b = 0; b < 4; ++b) acc[a][b] = 0.0f;

    for (int k = 0; k < 128; ++k) {
        const float4 w = *(const float4*)&W2[k * 128 + j0];
        #pragma unroll
        for (int ii = 0; ii < 4; ++ii) {
            float x = H[(i0 + ii) * 128 + k];
            acc[ii][0] = fmaf(x, w.x, acc[ii][0]);
            acc[ii][1] = fmaf(x, w.y, acc[ii][1]);
            acc[ii][2] = fmaf(x, w.z, acc[ii][2]);
            acc[ii][3] = fmaf(x, w.w, acc[ii][3]);
        }
    }
    const float4 bb2 = *(const float4*)&b2[j0];
    float* __restrict__ MSG = XB + 32 * 128;   // disjoint from H region
    #pragma unroll
    for (int ii = 0; ii < 4; ++ii) {
        float4 m;
        m.x = acc[ii][0] + bb2.x;
        m.y = acc[ii][1] + bb2.y;
        m.z = acc[ii][2] + bb2.z;
        m.w = acc[ii][3] + bb2.w;
        *(float4*)&MSG[(i0 + ii) * 128 + j0] = m;
    }
    __syncthreads();

    // ---- GRU: three gate passes (r, z, n) ----
    float4 accI[4], accH[4], rg[4], zg[4];

    // gate r
    #pragma unroll
    for (int ii = 0; ii < 4; ++ii) { accI[ii] = make_float4(0,0,0,0); accH[ii] = make_float4(0,0,0,0); }
    for (int k = 0; k < 128; ++k) {
        const float4 wi = *(const float4*)&WihT[k * 384 + j0];
        const float4 wh = *(const float4*)&WhhT[k * 384 + j0];
        #pragma unroll
        for (int ii = 0; ii < 4; ++ii) {
            float m = MSG[(i0 + ii) * 128 + k];
            float h = XA[(i0 + ii) * 128 + k];
            accI[ii].x = fmaf(m, wi.x, accI[ii].x); accI[ii].y = fmaf(m, wi.y, accI[ii].y);
            accI[ii].z = fmaf(m, wi.z, accI[ii].z); accI[ii].w = fmaf(m, wi.w, accI[ii].w);
            accH[ii].x = fmaf(h, wh.x, accH[ii].x); accH[ii].y = fmaf(h, wh.y, accH[ii].y);
            accH[ii].z = fmaf(h, wh.z, accH[ii].z); accH[ii].w = fmaf(h, wh.w, accH[ii].w);
        }
    }
    {
        const float4 bi = *(const float4*)&bih[j0];
        const float4 bh = *(const float4*)&bhh[j0];
        #pragma unroll
        for (int ii = 0; ii < 4; ++ii) {
            rg[ii].x = sigm(accI[ii].x + bi.x + accH[ii].x + bh.x);
            rg[ii].y = sigm(accI[ii].y + bi.y + accH[ii].y + bh.y);
            rg[ii].z = sigm(accI[ii].z + bi.z + accH[ii].z + bh.z);
            rg[ii].w = sigm(accI[ii].w + bi.w + accH[ii].w + bh.w);
        }
    }

    // gate z
    #pragma unroll
    for (int ii = 0; ii < 4; ++ii) { accI[ii] = make_float4(0,0,0,0); accH[ii] = make_float4(0,0,0,0); }
    for (int k = 0; k < 128; ++k) {
        const float4 wi = *(const float4*)&WihT[k * 384 + 128 + j0];
        const float4 wh = *(const float4*)&WhhT[k * 384 + 128 + j0];
        #pragma unroll
        for (int ii = 0; ii < 4; ++ii) {
            float m = MSG[(i0 + ii) * 128 + k];
            float h = XA[(i0 + ii) * 128 + k];
            accI[ii].x = fmaf(m, wi.x, accI[ii].x); accI[ii].y = fmaf(m, wi.y, accI[ii].y);
            accI[ii].z = fmaf(m, wi.z, accI[ii].z); accI[ii].w = fmaf(m, wi.w, accI[ii].w);
            accH[ii].x = fmaf(h, wh.x, accH[ii].x); accH[ii].y = fmaf(h, wh.y, accH[ii].y);
            accH[ii].z = fmaf(h, wh.z, accH[ii].z); accH[ii].w = fmaf(h, wh.w, accH[ii].w);
        }
    }
    {
        const float4 bi = *(const float4*)&bih[128 + j0];
        const float4 bh = *(const float4*)&bhh[128 + j0];
        #pragma unroll
        for (int ii = 0; ii < 4; ++ii) {
            zg[ii].x = sigm(accI[ii].x + bi.x + accH[ii].x + bh.x);
            zg[ii].y = sigm(accI[ii].y + bi.y + accH[ii].y + bh.y);
            zg[ii].z = sigm(accI[ii].z + bi.z + accH[ii].z + bh.z);
            zg[ii].w = sigm(accI[ii].w + bi.w + accH[ii].w + bh.w);
        }
    }

    // gate n + output
    #pragma unroll
    for (int ii = 0; ii < 4; ++ii) { accI[ii] = make_float4(0,0,0,0); accH[ii] = make_float4(0,0,0,0); }
    for (int k = 0; k < 128; ++k) {
        const float4 wi = *(const float4*)&WihT[k * 384 + 256 + j0];
        const float4 wh = *(const float4*)&WhhT[k * 384 + 256 + j0];
        #pragma unroll
        for (int ii = 0; ii < 4; ++ii) {
            float m = MSG[(i0 + ii) * 128 + k];
            float h = XA[(i0 + ii) * 128 + k];
            accI[ii].x = fmaf(m, wi.x, accI[ii].x); accI[ii].y = fmaf(m, wi.y, accI[ii].y);
            accI[ii].z = fmaf(m, wi.z, accI[ii].z); accI[ii].w = fmaf(m, wi.w, accI[ii].w);
            accH[ii].x = fmaf(h, wh.x, accH[ii].x); accH[ii].y = fmaf(h, wh.y, accH[ii].y);
            accH[ii].z = fmaf(h, wh.z, accH[ii].z); accH[ii].w = fmaf(h, wh.w, accH[ii].w);
        }
    }
    {
        const float4 bi = *(const float4*)&bih[256 + j0];
        const float4 bh = *(const float4*)&bhh[256 + j0];
        #pragma unroll
        for (int ii = 0; ii < 4; ++ii) {
            if (i0 + ii < nt) {
                const float4 hcur = *(const float4*)&XA[(i0 + ii) * 128 + j0];
                float4 o;
                float nx;
                nx  = tanhf(accI[ii].x + bi.x + rg[ii].x * (accH[ii].x + bh.x));
                o.x = (1.0f - zg[ii].x) * nx + zg[ii].x * hcur.x;
                nx  = tanhf(accI[ii].y + bi.y + rg[ii].y * (accH[ii].y + bh.y));
                o.y = (1.0f - zg[ii].y) * nx + zg[ii].y * hcur.y;
                nx  = tanhf(accI[ii].z + bi.z + rg[ii].z * (accH[ii].z + bh.z));
                o.z = (1.0f - zg[ii].z) * nx + zg[ii].z * hcur.z;
                nx  = tanhf(accI[ii].w + bi.w + rg[ii].w * (accH[ii].w + bh.w));
                o.w = (1.0f - zg[ii].w) * nx + zg[ii].w * hcur.w;
                int n = snode[i0 + ii];
                *(float4*)&out[n * 128 + j0] = o;
            }
        }
    }
}

extern "C" void kernel_launch(void* const* d_in, const int* in_sizes, int n_in,
                              void* d_out, int out_size, void* d_ws, size_t ws_size,
                              hipStream_t stream) {
    const int*   src  = (const int*)d_in[0];
    const int*   dst  = (const int*)d_in[1];
    const float* ef   = (const float*)d_in[2];
    const float* ts   = (const float*)d_in[3];
    const float* mem  = (const float*)d_in[4];
    const float* lut  = (const float*)d_in[5];
    const float* tw   = (const float*)d_in[6];
    const float* tphi = (const float*)d_in[7];
    const float* W1   = (const float*)d_in[8];
    const float* b1   = (const float*)d_in[9];
    const float* W2   = (const float*)d_in[10];
    const float* b2   = (const float*)d_in[11];
    const float* Wih  = (const float*)d_in[12];
    const float* Whh  = (const float*)d_in[13];
    const float* bih  = (const float*)d_in[14];
    const float* bhh  = (const float*)d_in[15];
    float* out = (float*)d_out;

    char* ws = (char*)d_ws;
    int*   last_pos = (int*)ws;                      // NN ints
    int*   plist    = (int*)(ws + (size_t)NN * 4);   // NN ints
    int*   cnt      = (int*)(ws + (size_t)2 * NN * 4);
    float* WihT     = (float*)(ws + (size_t)2 * NN * 4 + 16);
    float* WhhT     = WihT + 384 * 128;

    // re-init scratch every call (harness does not re-poison between replays)
    hipMemsetAsync(last_pos, 0xFF, (size_t)NN * sizeof(int), stream);  // -1
    hipMemsetAsync(cnt, 0, sizeof(int), stream);

    k_transpose<<<(384 * 128 + 255) / 256, 256, 0, stream>>>(Wih, Whh, WihT, WhhT);
    k_scatter<<<(2 * NE + 255) / 256, 256, 0, stream>>>(src, dst, last_pos);
    k_compact<<<(NN + 255) / 256, 256, 0, stream>>>(last_pos, plist, cnt);
    k_copy_absent<<<(NN * 32 + 255) / 256, 256, 0, stream>>>(mem, last_pos, out);
    k_main<<<(NN + 31) / 32, 256, 0, stream>>>(plist, cnt, last_pos, src, dst, ef, ts,
                                               mem, lut, tw, tphi, W1, b1, W2, b2,
                                               WihT, WhhT, bih, bhh, out);
}

// Round 2
// 436.256 us; speedup vs baseline: 2.7996x; 2.7996x over previous
//
#include <hip/hip_runtime.h>
#include <hip/hip_bf16.h>
#include <math.h>

#define NN 200000
#define NE 200000

typedef __attribute__((ext_vector_type(8))) short bf16x8;
typedef __attribute__((ext_vector_type(4))) float f32x4;

__device__ __forceinline__ float sigm(float x) { return 1.0f / (1.0f + expf(-x)); }

__device__ __forceinline__ ushort f2b(float x) {
    union { __hip_bfloat16 b; ushort u; } v;
    v.b = __float2bfloat16(x);
    return v.u;
}

#define MFMA16(a, b, c) __builtin_amdgcn_mfma_f32_16x16x32_bf16((a), (b), (c), 0, 0, 0)

// -------- last_pos via atomicMax (== segment_max of positions) --------
__global__ void k_scatter(const int* __restrict__ src, const int* __restrict__ dst,
                          int* __restrict__ last_pos) {
    int i = blockIdx.x * blockDim.x + threadIdx.x;
    if (i < NE) {
        atomicMax(&last_pos[src[i]], i);
    } else if (i < 2 * NE) {
        atomicMax(&last_pos[dst[i - NE]], i);
    }
}

// -------- compact present nodes --------
__global__ void k_compact(const int* __restrict__ last_pos, int* __restrict__ plist,
                          int* __restrict__ cnt) {
    int n = blockIdx.x * blockDim.x + threadIdx.x;
    if (n < NN && last_pos[n] >= 0) {
        int idx = atomicAdd(cnt, 1);
        plist[idx] = n;
    }
}

// -------- absent nodes: out = memory --------
__global__ void k_copy_absent(const float* __restrict__ mem, const int* __restrict__ last_pos,
                              float* __restrict__ out) {
    int t = blockIdx.x * blockDim.x + threadIdx.x;
    int node = t >> 5;
    if (node >= NN) return;
    if (last_pos[node] < 0) {
        int c = (t & 31) * 4;
        *(float4*)&out[(size_t)node * 128 + c] = *(const float4*)&mem[(size_t)node * 128 + c];
    }
}

// -------- weight prep: fp32 -> bf16, B-fragment-friendly [n][k] layouts --------
// W1T: [128][416] (n-major, k-contig, k>=400 zero)   53248 u16
// W2T: [128][128]                                    16384 u16
// WI : [384][128]  (= W_ih as-is, bf16)              49152 u16
// WH : [384][128]                                    49152 u16
__global__ void k_prepw(const float* __restrict__ W1, const float* __restrict__ W2,
                        const float* __restrict__ Wih, const float* __restrict__ Whh,
                        ushort* __restrict__ W1T, ushort* __restrict__ W2T,
                        ushort* __restrict__ WI, ushort* __restrict__ WH) {
    int i = blockIdx.x * blockDim.x + threadIdx.x;
    if (i < 128 * 416) {
        int n = i / 416, k = i % 416;
        W1T[i] = (k < 400) ? f2b(W1[k * 128 + n]) : (ushort)0;
        return;
    }
    i -= 128 * 416;
    if (i < 128 * 128) { int n = i >> 7, k = i & 127; W2T[i] = f2b(W2[k * 128 + n]); return; }
    i -= 128 * 128;
    if (i < 384 * 128) { WI[i] = f2b(Wih[i]); return; }
    i -= 384 * 128;
    if (i < 384 * 128) { WH[i] = f2b(Whh[i]); }
}

// -------- main: 32 nodes/block, MFMA bf16 message MLP + GRU --------
#define XSTR 440   // X row stride (u16): 416 used + pad -> 2-way-free LDS banks
#define HSTR 136   // H/MSG row stride

__global__ __launch_bounds__(256, 3)
void k_main(const int* __restrict__ plist, const int* __restrict__ cnt_p,
            const int* __restrict__ last_pos,
            const int* __restrict__ src, const int* __restrict__ dst,
            const float* __restrict__ ef, const float* __restrict__ ts,
            const float* __restrict__ mem, const float* __restrict__ lut,
            const float* __restrict__ tw, const float* __restrict__ tphi,
            const ushort* __restrict__ W1T, const float* __restrict__ b1,
            const ushort* __restrict__ W2T, const float* __restrict__ b2,
            const ushort* __restrict__ WI, const ushort* __restrict__ WH,
            const float* __restrict__ bih, const float* __restrict__ bhh,
            float* __restrict__ out)
{
    __shared__ ushort XH[32 * XSTR];   // x rows: [mem[n] | mem[other] | ef | te | 0pad]
    __shared__ ushort Hh[32 * HSTR];   // relu(L1) bf16
    __shared__ ushort Mh[32 * HSTR];   // msg bf16
    __shared__ int snode[32];

    const int cnt  = *cnt_p;
    const int base = blockIdx.x * 32;
    if (base >= cnt) return;
    const int nt   = min(32, cnt - base);
    const int tid  = threadIdx.x;
    const int lane = tid & 63;
    const int wv   = tid >> 6;

    // ---- stage X rows (one wave per node), fp32 -> bf16 ----
    for (int i = wv; i < nt; i += 4) {
        int n = plist[base + i];
        if (lane == 0) snode[i] = n;
        int p = last_pos[n];
        int e, other;
        if (p < NE) { e = p;      other = dst[e]; }
        else        { e = p - NE; other = src[e]; }
        {   // cols 0..255: mem[n] | mem[other]
            const float* sp = (lane < 32) ? &mem[(size_t)n * 128 + lane * 4]
                                          : &mem[(size_t)other * 128 + (lane - 32) * 4];
            float4 v = *(const float4*)sp;
            ushort4 u; u.x = f2b(v.x); u.y = f2b(v.y); u.z = f2b(v.z); u.w = f2b(v.w);
            *(ushort4*)&XH[i * XSTR + lane * 4] = u;
        }
        if (lane < 32) {   // cols 256..383: edge_feat
            float4 v = *(const float4*)&ef[(size_t)e * 128 + lane * 4];
            ushort4 u; u.x = f2b(v.x); u.y = f2b(v.y); u.z = f2b(v.z); u.w = f2b(v.w);
            *(ushort4*)&XH[i * XSTR + 256 + lane * 4] = u;
        } else {           // cols 384..399: time enc; 400..415: zero
            int k = lane - 32;   // 0..31
            float val = 0.0f;
            if (k < 16) {
                float dtv = ts[e] - lut[n];
                float wt = fmaf(dtv, tw[k], tphi[k]);
                val = (k == 0) ? wt : sinf(wt);
            }
            XH[i * XSTR + 384 + k] = f2b(val);
        }
    }
    __syncthreads();

    const int r16 = lane & 15;
    const int kb  = lane >> 4;

    // ---- layer 1: h1 = relu(x @ W1 + b1), M=32 N=128 K=416 ----
    f32x4 c1[2][2] = {};   // [m][nsub]
    {
        const ushort* aA = &XH[r16 * XSTR + kb * 8];
        const ushort* bp = &W1T[(size_t)(wv * 32 + r16) * 416 + kb * 8];
        #pragma unroll
        for (int kt = 0; kt < 13; ++kt) {
            bf16x8 A0 = *(const bf16x8*)(aA + kt * 32);
            bf16x8 A1 = *(const bf16x8*)(aA + 16 * XSTR + kt * 32);
            bf16x8 B0 = *(const bf16x8*)(bp + kt * 32);
            bf16x8 B1 = *(const bf16x8*)(bp + 16 * 416 + kt * 32);
            c1[0][0] = MFMA16(A0, B0, c1[0][0]);
            c1[0][1] = MFMA16(A0, B1, c1[0][1]);
            c1[1][0] = MFMA16(A1, B0, c1[1][0]);
            c1[1][1] = MFMA16(A1, B1, c1[1][1]);
        }
    }
    #pragma unroll
    for (int ns = 0; ns < 2; ++ns) {
        int col = wv * 32 + ns * 16 + r16;
        float bb = b1[col];
        #pragma unroll
        for (int m = 0; m < 2; ++m)
            #pragma unroll
            for (int r = 0; r < 4; ++r)
                Hh[(m * 16 + kb * 4 + r) * HSTR + col] = f2b(fmaxf(c1[m][ns][r] + bb, 0.0f));
    }
    __syncthreads();

    // ---- layer 2: msg = h1 @ W2 + b2, K=128 ----
    f32x4 c2[2][2] = {};
    {
        const ushort* aA = &Hh[r16 * HSTR + kb * 8];
        const ushort* bp = &W2T[(size_t)(wv * 32 + r16) * 128 + kb * 8];
        #pragma unroll
        for (int kt = 0; kt < 4; ++kt) {
            bf16x8 A0 = *(const bf16x8*)(aA + kt * 32);
            bf16x8 A1 = *(const bf16x8*)(aA + 16 * HSTR + kt * 32);
            bf16x8 B0 = *(const bf16x8*)(bp + kt * 32);
            bf16x8 B1 = *(const bf16x8*)(bp + 16 * 128 + kt * 32);
            c2[0][0] = MFMA16(A0, B0, c2[0][0]);
            c2[0][1] = MFMA16(A0, B1, c2[0][1]);
            c2[1][0] = MFMA16(A1, B0, c2[1][0]);
            c2[1][1] = MFMA16(A1, B1, c2[1][1]);
        }
    }
    #pragma unroll
    for (int ns = 0; ns < 2; ++ns) {
        int col = wv * 32 + ns * 16 + r16;
        float bb = b2[col];
        #pragma unroll
        for (int m = 0; m < 2; ++m)
            #pragma unroll
            for (int r = 0; r < 4; ++r)
                Mh[(m * 16 + kb * 4 + r) * HSTR + col] = f2b(c2[m][ns][r] + bb);
    }
    __syncthreads();

    // ---- GRU: gi = msg @ WI^T-layout, gh = h @ WH; r/z share acc, n split ----
    f32x4 arz[2][4] = {};   // [m][gate*2+ns]  (i_g + h_g summed)
    f32x4 an_i[2][2] = {};  // [m][ns]
    f32x4 an_h[2][2] = {};
    {
        const ushort* am = &Mh[r16 * HSTR + kb * 8];
        const ushort* ah = &XH[r16 * XSTR + kb * 8];   // h = mem[n] = x cols 0..127
        const size_t cb = (size_t)(wv * 32 + r16) * 128 + kb * 8;
        const ushort* bi = WI + cb;
        const ushort* bh = WH + cb;
        #pragma unroll
        for (int kt = 0; kt < 4; ++kt) {
            bf16x8 M0 = *(const bf16x8*)(am + kt * 32);
            bf16x8 M1 = *(const bf16x8*)(am + 16 * HSTR + kt * 32);
            bf16x8 H0 = *(const bf16x8*)(ah + kt * 32);
            bf16x8 H1 = *(const bf16x8*)(ah + 16 * XSTR + kt * 32);
            #pragma unroll
            for (int g = 0; g < 2; ++g)
                #pragma unroll
                for (int ns = 0; ns < 2; ++ns) {
                    size_t off = (size_t)(g * 128 + ns * 16) * 128 + kt * 32;
                    bf16x8 Bi = *(const bf16x8*)(bi + off);
                    bf16x8 Bh = *(const bf16x8*)(bh + off);
                    arz[0][g * 2 + ns] = MFMA16(M0, Bi, arz[0][g * 2 + ns]);
                    arz[0][g * 2 + ns] = MFMA16(H0, Bh, arz[0][g * 2 + ns]);
                    arz[1][g * 2 + ns] = MFMA16(M1, Bi, arz[1][g * 2 + ns]);
                    arz[1][g * 2 + ns] = MFMA16(H1, Bh, arz[1][g * 2 + ns]);
                }
            #pragma unroll
            for (int ns = 0; ns < 2; ++ns) {
                size_t off = (size_t)(256 + ns * 16) * 128 + kt * 32;
                bf16x8 Bi = *(const bf16x8*)(bi + off);
                bf16x8 Bh = *(const bf16x8*)(bh + off);
                an_i[0][ns] = MFMA16(M0, Bi, an_i[0][ns]);
                an_i[1][ns] = MFMA16(M1, Bi, an_i[1][ns]);
                an_h[0][ns] = MFMA16(H0, Bh, an_h[0][ns]);
                an_h[1][ns] = MFMA16(H1, Bh, an_h[1][ns]);
            }
        }
    }

    // ---- epilogue: gates + blend + scattered store ----
    #pragma unroll
    for (int ns = 0; ns < 2; ++ns) {
        int col = wv * 32 + ns * 16 + r16;
        float brz0 = bih[col] + bhh[col];
        float brz1 = bih[128 + col] + bhh[128 + col];
        float bin  = bih[256 + col];
        float bhn  = bhh[256 + col];
        #pragma unroll
        for (int m = 0; m < 2; ++m) {
            #pragma unroll
            for (int r = 0; r < 4; ++r) {
                int row = m * 16 + kb * 4 + r;
                if (row < nt) {
                    int node = snode[row];
                    float rr = sigm(arz[m][0 + ns][r] + brz0);
                    float zz = sigm(arz[m][2 + ns][r] + brz1);
                    float nn = tanhf(an_i[m][ns][r] + bin + rr * (an_h[m][ns][r] + bhn));
                    float hh = mem[(size_t)node * 128 + col];
                    out[(size_t)node * 128 + col] = (1.0f - zz) * nn + zz * hh;
                }
            }
        }
    }
}

extern "C" void kernel_launch(void* const* d_in, const int* in_sizes, int n_in,
                              void* d_out, int out_size, void* d_ws, size_t ws_size,
                              hipStream_t stream) {
    const int*   src  = (const int*)d_in[0];
    const int*   dst  = (const int*)d_in[1];
    const float* ef   = (const float*)d_in[2];
    const float* ts   = (const float*)d_in[3];
    const float* mem  = (const float*)d_in[4];
    const float* lut  = (const float*)d_in[5];
    const float* tw   = (const float*)d_in[6];
    const float* tphi = (const float*)d_in[7];
    const float* W1   = (const float*)d_in[8];
    const float* b1   = (const float*)d_in[9];
    const float* W2   = (const float*)d_in[10];
    const float* b2   = (const float*)d_in[11];
    const float* Wih  = (const float*)d_in[12];
    const float* Whh  = (const float*)d_in[13];
    const float* bih  = (const float*)d_in[14];
    const float* bhh  = (const float*)d_in[15];
    float* out = (float*)d_out;

    char* ws = (char*)d_ws;
    int*    last_pos = (int*)ws;                        // NN ints
    int*    plist    = (int*)(ws + (size_t)NN * 4);     // NN ints
    int*    cnt      = (int*)(ws + (size_t)2 * NN * 4);
    ushort* W1T      = (ushort*)(ws + (size_t)2 * NN * 4 + 16);   // 16B-aligned
    ushort* W2T      = W1T + 128 * 416;
    ushort* WI       = W2T + 128 * 128;
    ushort* WH       = WI + 384 * 128;

    hipMemsetAsync(last_pos, 0xFF, (size_t)NN * sizeof(int), stream);  // -1
    hipMemsetAsync(cnt, 0, sizeof(int), stream);

    k_prepw<<<(128 * 416 + 128 * 128 + 2 * 384 * 128 + 255) / 256, 256, 0, stream>>>(
        W1, W2, Wih, Whh, W1T, W2T, WI, WH);
    k_scatter<<<(2 * NE + 255) / 256, 256, 0, stream>>>(src, dst, last_pos);
    k_compact<<<(NN + 255) / 256, 256, 0, stream>>>(last_pos, plist, cnt);
    k_copy_absent<<<(NN * 32 + 255) / 256, 256, 0, stream>>>(mem, last_pos, out);
    k_main<<<(NN + 31) / 32, 256, 0, stream>>>(plist, cnt, last_pos, src, dst, ef, ts,
                                               mem, lut, tw, tphi, W1T, b1, W2T, b2,
                                               WI, WH, bih, bhh, out);
}

// Round 3
// 422.830 us; speedup vs baseline: 2.8885x; 1.0318x over previous
//
#include <hip/hip_runtime.h>
#include <hip/hip_bf16.h>
#include <math.h>

#define NN 200000
#define NE 200000

typedef __attribute__((ext_vector_type(8))) short bf16x8;
typedef __attribute__((ext_vector_type(4))) float f32x4;

__device__ __forceinline__ float sigm(float x) { return 1.0f / (1.0f + expf(-x)); }

__device__ __forceinline__ ushort f2b(float x) {
    union { __hip_bfloat16 b; ushort u; } v;
    v.b = __float2bfloat16(x);
    return v.u;
}
__device__ __forceinline__ float b2f(ushort u) {
    return __uint_as_float(((unsigned)u) << 16);
}
__device__ __forceinline__ ushort4 cvt4(float4 v) {
    ushort4 u; u.x = f2b(v.x); u.y = f2b(v.y); u.z = f2b(v.z); u.w = f2b(v.w);
    return u;
}

#define MFMA16(a, b, c) __builtin_amdgcn_mfma_f32_16x16x32_bf16((a), (b), (c), 0, 0, 0)

// -------- last_pos via atomicMax (== segment_max of positions) --------
__global__ void k_scatter(const int* __restrict__ src, const int* __restrict__ dst,
                          int* __restrict__ last_pos) {
    int i = blockIdx.x * blockDim.x + threadIdx.x;
    if (i < NE) {
        atomicMax(&last_pos[src[i]], i);
    } else if (i < 2 * NE) {
        atomicMax(&last_pos[dst[i - NE]], i);
    }
}

// -------- compact present nodes + resolve full event info (kills dep chain) --------
__global__ void k_compact(const int* __restrict__ last_pos,
                          const int* __restrict__ src, const int* __restrict__ dst,
                          const float* __restrict__ ts, const float* __restrict__ lut,
                          int4* __restrict__ einfo, int* __restrict__ cnt) {
    int n = blockIdx.x * blockDim.x + threadIdx.x;
    if (n >= NN) return;
    int p = last_pos[n];
    if (p < 0) return;
    int e, other;
    if (p < NE) { e = p;      other = dst[e]; }
    else        { e = p - NE; other = src[e]; }
    float dt = ts[e] - lut[n];
    int idx = atomicAdd(cnt, 1);
    einfo[idx] = make_int4(n, e, other, __float_as_int(dt));
}

// -------- absent nodes: out = memory --------
__global__ void k_copy_absent(const float* __restrict__ mem, const int* __restrict__ last_pos,
                              float* __restrict__ out) {
    int t = blockIdx.x * blockDim.x + threadIdx.x;
    int node = t >> 5;
    if (node >= NN) return;
    if (last_pos[node] < 0) {
        int c = (t & 31) * 4;
        *(float4*)&out[(size_t)node * 128 + c] = *(const float4*)&mem[(size_t)node * 128 + c];
    }
}

// -------- weight prep: fp32 -> bf16, B-fragment-friendly [n][k] layouts --------
__global__ void k_prepw(const float* __restrict__ W1, const float* __restrict__ W2,
                        const float* __restrict__ Wih, const float* __restrict__ Whh,
                        ushort* __restrict__ W1T, ushort* __restrict__ W2T,
                        ushort* __restrict__ WI, ushort* __restrict__ WH) {
    int i = blockIdx.x * blockDim.x + threadIdx.x;
    if (i < 128 * 416) {
        int n = i / 416, k = i % 416;
        W1T[i] = (k < 400) ? f2b(W1[k * 128 + n]) : (ushort)0;
        return;
    }
    i -= 128 * 416;
    if (i < 128 * 128) { int n = i >> 7, k = i & 127; W2T[i] = f2b(W2[k * 128 + n]); return; }
    i -= 128 * 128;
    if (i < 384 * 128) { WI[i] = f2b(Wih[i]); return; }
    i -= 384 * 128;
    if (i < 384 * 128) { WH[i] = f2b(Whh[i]); }
}

// -------- main: 32 nodes/block, MFMA bf16 message MLP + GRU --------
#define XASTR 136   // XA row stride (u16): mem[n], 128 used
#define XBSTR 296   // XB row stride (u16): other(128)|ef(128)|te(16)|zero(16) = 288 used
// XB reuse after L1 reads: H -> cols 0..127, MSG -> cols 136..263

__global__ __launch_bounds__(256, 5)
void k_main(const int4* __restrict__ einfo, const int* __restrict__ cnt_p,
            const float* __restrict__ ef,
            const float* __restrict__ mem,
            const float* __restrict__ tw, const float* __restrict__ tphi,
            const ushort* __restrict__ W1T, const float* __restrict__ b1,
            const ushort* __restrict__ W2T, const float* __restrict__ b2,
            const ushort* __restrict__ WI, const ushort* __restrict__ WH,
            const float* __restrict__ bih, const float* __restrict__ bhh,
            float* __restrict__ out)
{
    __shared__ ushort XA[32 * XASTR];
    __shared__ ushort XB[32 * XBSTR];
    __shared__ int snode[32];

    const int cnt  = *cnt_p;
    const int base = blockIdx.x * 32;
    if (base >= cnt) return;
    const int nt   = min(32, cnt - base);
    const int tid  = threadIdx.x;
    const int lane = tid & 63;
    const int wv   = tid >> 6;

    // ---- stage (one wave per node): depth-1 indirection via einfo ----
    for (int i = wv; i < nt; i += 4) {
        int4 ei = einfo[base + i];
        int n = ei.x, e = ei.y, other = ei.z;
        float dtv = __int_as_float(ei.w);
        if (lane == 0) snode[i] = n;
        if (lane < 32) {
            float4 v = *(const float4*)&mem[(size_t)n * 128 + lane * 4];
            *(ushort4*)&XA[i * XASTR + lane * 4] = cvt4(v);
            float4 w = *(const float4*)&ef[(size_t)e * 128 + lane * 4];
            *(ushort4*)&XB[i * XBSTR + 128 + lane * 4] = cvt4(w);
        } else {
            int l = lane - 32;
            float4 v = *(const float4*)&mem[(size_t)other * 128 + l * 4];
            *(ushort4*)&XB[i * XBSTR + l * 4] = cvt4(v);
            float val = 0.0f;
            if (l < 16) {
                float wt = fmaf(dtv, tw[l], tphi[l]);
                val = (l == 0) ? wt : sinf(wt);
            }
            XB[i * XBSTR + 256 + l] = f2b(val);   // te(16) + zero(16)
        }
    }
    __syncthreads();

    const int r16 = lane & 15;
    const int kb  = lane >> 4;

    // ---- layer 1: h1 = relu(x @ W1 + b1), M=32 N=128 K=416 ----
    f32x4 c1[2][2] = {};
    {
        const ushort* aA = &XA[r16 * XASTR + kb * 8];
        const ushort* aB = &XB[r16 * XBSTR + kb * 8];
        const ushort* bp = &W1T[(size_t)(wv * 32 + r16) * 416 + kb * 8];
        #pragma unroll
        for (int kt = 0; kt < 13; ++kt) {
            const ushort* ap  = (kt < 4) ? (aA + kt * 32) : (aB + (kt - 4) * 32);
            const int     ast = (kt < 4) ? XASTR : XBSTR;
            bf16x8 A0 = *(const bf16x8*)ap;
            bf16x8 A1 = *(const bf16x8*)(ap + 16 * ast);
            bf16x8 B0 = *(const bf16x8*)(bp + kt * 32);
            bf16x8 B1 = *(const bf16x8*)(bp + 16 * 416 + kt * 32);
            c1[0][0] = MFMA16(A0, B0, c1[0][0]);
            c1[0][1] = MFMA16(A0, B1, c1[0][1]);
            c1[1][0] = MFMA16(A1, B0, c1[1][0]);
            c1[1][1] = MFMA16(A1, B1, c1[1][1]);
        }
    }
    __syncthreads();   // all XB reads done; safe to overwrite with H

    #pragma unroll
    for (int ns = 0; ns < 2; ++ns) {
        int col = wv * 32 + ns * 16 + r16;
        float bb = b1[col];
        #pragma unroll
        for (int m = 0; m < 2; ++m)
            #pragma unroll
            for (int r = 0; r < 4; ++r)
                XB[(m * 16 + kb * 4 + r) * XBSTR + col] = f2b(fmaxf(c1[m][ns][r] + bb, 0.0f));
    }
    __syncthreads();

    // ---- layer 2: msg = h1 @ W2 + b2, K=128; write MSG to disjoint XB cols ----
    f32x4 c2[2][2] = {};
    {
        const ushort* aA = &XB[r16 * XBSTR + kb * 8];
        const ushort* bp = &W2T[(size_t)(wv * 32 + r16) * 128 + kb * 8];
        #pragma unroll
        for (int kt = 0; kt < 4; ++kt) {
            bf16x8 A0 = *(const bf16x8*)(aA + kt * 32);
            bf16x8 A1 = *(const bf16x8*)(aA + 16 * XBSTR + kt * 32);
            bf16x8 B0 = *(const bf16x8*)(bp + kt * 32);
            bf16x8 B1 = *(const bf16x8*)(bp + 16 * 128 + kt * 32);
            c2[0][0] = MFMA16(A0, B0, c2[0][0]);
            c2[0][1] = MFMA16(A0, B1, c2[0][1]);
            c2[1][0] = MFMA16(A1, B0, c2[1][0]);
            c2[1][1] = MFMA16(A1, B1, c2[1][1]);
        }
    }
    // MSG region (cols 136..263) is disjoint from H read region (0..127): no sync needed
    #pragma unroll
    for (int ns = 0; ns < 2; ++ns) {
        int col = wv * 32 + ns * 16 + r16;
        float bb = b2[col];
        #pragma unroll
        for (int m = 0; m < 2; ++m)
            #pragma unroll
            for (int r = 0; r < 4; ++r)
                XB[(m * 16 + kb * 4 + r) * XBSTR + 136 + col] = f2b(c2[m][ns][r] + bb);
    }
    __syncthreads();

    // ---- GRU ----
    f32x4 arz[2][4] = {};   // [m][gate*2+ns]
    f32x4 an_i[2][2] = {};
    f32x4 an_h[2][2] = {};
    {
        const ushort* am = &XB[r16 * XBSTR + 136 + kb * 8];
        const ushort* ah = &XA[r16 * XASTR + kb * 8];
        const size_t cb = (size_t)(wv * 32 + r16) * 128 + kb * 8;
        const ushort* bi = WI + cb;
        const ushort* bh = WH + cb;
        #pragma unroll
        for (int kt = 0; kt < 4; ++kt) {
            bf16x8 M0 = *(const bf16x8*)(am + kt * 32);
            bf16x8 M1 = *(const bf16x8*)(am + 16 * XBSTR + kt * 32);
            bf16x8 H0 = *(const bf16x8*)(ah + kt * 32);
            bf16x8 H1 = *(const bf16x8*)(ah + 16 * XASTR + kt * 32);
            #pragma unroll
            for (int g = 0; g < 2; ++g)
                #pragma unroll
                for (int ns = 0; ns < 2; ++ns) {
                    size_t off = (size_t)(g * 128 + ns * 16) * 128 + kt * 32;
                    bf16x8 Bi = *(const bf16x8*)(bi + off);
                    bf16x8 Bh = *(const bf16x8*)(bh + off);
                    arz[0][g * 2 + ns] = MFMA16(M0, Bi, arz[0][g * 2 + ns]);
                    arz[0][g * 2 + ns] = MFMA16(H0, Bh, arz[0][g * 2 + ns]);
                    arz[1][g * 2 + ns] = MFMA16(M1, Bi, arz[1][g * 2 + ns]);
                    arz[1][g * 2 + ns] = MFMA16(H1, Bh, arz[1][g * 2 + ns]);
                }
            #pragma unroll
            for (int ns = 0; ns < 2; ++ns) {
                size_t off = (size_t)(256 + ns * 16) * 128 + kt * 32;
                bf16x8 Bi = *(const bf16x8*)(bi + off);
                bf16x8 Bh = *(const bf16x8*)(bh + off);
                an_i[0][ns] = MFMA16(M0, Bi, an_i[0][ns]);
                an_i[1][ns] = MFMA16(M1, Bi, an_i[1][ns]);
                an_h[0][ns] = MFMA16(H0, Bh, an_h[0][ns]);
                an_h[1][ns] = MFMA16(H1, Bh, an_h[1][ns]);
            }
        }
    }

    // ---- epilogue: gates + blend; h read back from XA (bf16) ----
    #pragma unroll
    for (int ns = 0; ns < 2; ++ns) {
        int col = wv * 32 + ns * 16 + r16;
        float brz0 = bih[col] + bhh[col];
        float brz1 = bih[128 + col] + bhh[128 + col];
        float bin  = bih[256 + col];
        float bhn  = bhh[256 + col];
        #pragma unroll
        for (int m = 0; m < 2; ++m) {
            #pragma unroll
            for (int r = 0; r < 4; ++r) {
                int row = m * 16 + kb * 4 + r;
                if (row < nt) {
                    float rr = sigm(arz[m][0 + ns][r] + brz0);
                    float zz = sigm(arz[m][2 + ns][r] + brz1);
                    float nn = tanhf(an_i[m][ns][r] + bin + rr * (an_h[m][ns][r] + bhn));
                    float hh = b2f(XA[row * XASTR + col]);
                    out[(size_t)snode[row] * 128 + col] = (1.0f - zz) * nn + zz * hh;
                }
            }
        }
    }
}

extern "C" void kernel_launch(void* const* d_in, const int* in_sizes, int n_in,
                              void* d_out, int out_size, void* d_ws, size_t ws_size,
                              hipStream_t stream) {
    const int*   src  = (const int*)d_in[0];
    const int*   dst  = (const int*)d_in[1];
    const float* ef   = (const float*)d_in[2];
    const float* ts   = (const float*)d_in[3];
    const float* mem  = (const float*)d_in[4];
    const float* lut  = (const float*)d_in[5];
    const float* tw   = (const float*)d_in[6];
    const float* tphi = (const float*)d_in[7];
    const float* W1   = (const float*)d_in[8];
    const float* b1   = (const float*)d_in[9];
    const float* W2   = (const float*)d_in[10];
    const float* b2   = (const float*)d_in[11];
    const float* Wih  = (const float*)d_in[12];
    const float* Whh  = (const float*)d_in[13];
    const float* bih  = (const float*)d_in[14];
    const float* bhh  = (const float*)d_in[15];
    float* out = (float*)d_out;

    char* ws = (char*)d_ws;
    int*    last_pos = (int*)ws;                                   // NN ints
    int4*   einfo    = (int4*)(ws + (size_t)NN * 4);               // NN int4 (16B-aligned)
    int*    cnt      = (int*)(ws + (size_t)NN * 4 + (size_t)NN * 16);
    ushort* W1T      = (ushort*)(ws + (size_t)NN * 4 + (size_t)NN * 16 + 16);
    ushort* W2T      = W1T + 128 * 416;
    ushort* WI       = W2T + 128 * 128;
    ushort* WH       = WI + 384 * 128;

    hipMemsetAsync(last_pos, 0xFF, (size_t)NN * sizeof(int), stream);  // -1
    hipMemsetAsync(cnt, 0, sizeof(int), stream);

    k_prepw<<<(128 * 416 + 128 * 128 + 2 * 384 * 128 + 255) / 256, 256, 0, stream>>>(
        W1, W2, Wih, Whh, W1T, W2T, WI, WH);
    k_scatter<<<(2 * NE + 255) / 256, 256, 0, stream>>>(src, dst, last_pos);
    k_compact<<<(NN + 255) / 256, 256, 0, stream>>>(last_pos, src, dst, ts, lut, einfo, cnt);
    k_copy_absent<<<(NN * 32 + 255) / 256, 256, 0, stream>>>(mem, last_pos, out);
    k_main<<<(NN + 31) / 32, 256, 0, stream>>>(einfo, cnt, ef, mem, tw, tphi,
                                               W1T, b1, W2T, b2, WI, WH, bih, bhh, out);
}

// Round 4
// 382.955 us; speedup vs baseline: 3.1892x; 1.1041x over previous
//
#include <hip/hip_runtime.h>
#include <hip/hip_bf16.h>
#include <math.h>

#define NN 200000
#define NE 200000

typedef __attribute__((ext_vector_type(8))) short bf16x8;
typedef __attribute__((ext_vector_type(4))) float f32x4;

__device__ __forceinline__ float sigm(float x) { return 1.0f / (1.0f + expf(-x)); }

__device__ __forceinline__ ushort f2b(float x) {
    union { __hip_bfloat16 b; ushort u; } v;
    v.b = __float2bfloat16(x);
    return v.u;
}
__device__ __forceinline__ float b2f(ushort u) {
    return __uint_as_float(((unsigned)u) << 16);
}
__device__ __forceinline__ ushort4 cvt4(float4 v) {
    ushort4 u; u.x = f2b(v.x); u.y = f2b(v.y); u.z = f2b(v.z); u.w = f2b(v.w);
    return u;
}

#define MFMA16(a, b, c) __builtin_amdgcn_mfma_f32_16x16x32_bf16((a), (b), (c), 0, 0, 0)

// -------- last_pos via atomicMax (== segment_max of positions) --------
__global__ void k_scatter(const int* __restrict__ src, const int* __restrict__ dst,
                          int* __restrict__ last_pos) {
    int i = blockIdx.x * blockDim.x + threadIdx.x;
    if (i < NE) {
        atomicMax(&last_pos[src[i]], i);
    } else if (i < 2 * NE) {
        atomicMax(&last_pos[dst[i - NE]], i);
    }
}

// -------- compact present nodes + resolve full event info (kills dep chain) --------
__global__ void k_compact(const int* __restrict__ last_pos,
                          const int* __restrict__ src, const int* __restrict__ dst,
                          const float* __restrict__ ts, const float* __restrict__ lut,
                          int4* __restrict__ einfo, int* __restrict__ cnt) {
    int n = blockIdx.x * blockDim.x + threadIdx.x;
    if (n >= NN) return;
    int p = last_pos[n];
    if (p < 0) return;
    int e, other;
    if (p < NE) { e = p;      other = dst[e]; }
    else        { e = p - NE; other = src[e]; }
    float dt = ts[e] - lut[n];
    int idx = atomicAdd(cnt, 1);
    einfo[idx] = make_int4(n, e, other, __float_as_int(dt));
}

// -------- absent nodes: out = memory --------
__global__ void k_copy_absent(const float* __restrict__ mem, const int* __restrict__ last_pos,
                              float* __restrict__ out) {
    int t = blockIdx.x * blockDim.x + threadIdx.x;
    int node = t >> 5;
    if (node >= NN) return;
    if (last_pos[node] < 0) {
        int c = (t & 31) * 4;
        *(float4*)&out[(size_t)node * 128 + c] = *(const float4*)&mem[(size_t)node * 128 + c];
    }
}

// -------- weight prep: fp32 -> bf16, B-fragment-friendly [n][k] layouts --------
__global__ void k_prepw(const float* __restrict__ W1, const float* __restrict__ W2,
                        const float* __restrict__ Wih, const float* __restrict__ Whh,
                        ushort* __restrict__ W1T, ushort* __restrict__ W2T,
                        ushort* __restrict__ WI, ushort* __restrict__ WH) {
    int i = blockIdx.x * blockDim.x + threadIdx.x;
    if (i < 128 * 416) {
        int n = i / 416, k = i % 416;
        W1T[i] = (k < 400) ? f2b(W1[k * 128 + n]) : (ushort)0;
        return;
    }
    i -= 128 * 416;
    if (i < 128 * 128) { int n = i >> 7, k = i & 127; W2T[i] = f2b(W2[k * 128 + n]); return; }
    i -= 128 * 128;
    if (i < 384 * 128) { WI[i] = f2b(Wih[i]); return; }
    i -= 384 * 128;
    if (i < 384 * 128) { WH[i] = f2b(Whh[i]); }
}

// -------- main: 32 nodes/block, MFMA bf16 message MLP + GRU --------
#define XASTR 136   // XA row stride (u16): mem[n], 128 used
#define XBSTR 296   // XB row stride (u16): other(128)|ef(128)|te(16)|zero(16) = 288 used
#define OSTR  132   // f32 output-stage row stride (in XB reuse)
// XB reuse after L1 reads: H -> cols 0..127, MSG -> cols 136..263
// XB reuse after GRU: f32 out rows [32][OSTR]  (32*132*4 = 16896 B <= 18944 B)

__global__ __launch_bounds__(256, 4)
void k_main(const int4* __restrict__ einfo, const int* __restrict__ cnt_p,
            const float* __restrict__ ef,
            const float* __restrict__ mem,
            const float* __restrict__ tw, const float* __restrict__ tphi,
            const ushort* __restrict__ W1T, const float* __restrict__ b1,
            const ushort* __restrict__ W2T, const float* __restrict__ b2,
            const ushort* __restrict__ WI, const ushort* __restrict__ WH,
            const float* __restrict__ bih, const float* __restrict__ bhh,
            float* __restrict__ out)
{
    __shared__ __align__(16) ushort XA[32 * XASTR];
    __shared__ __align__(16) ushort XB[32 * XBSTR];
    __shared__ int snode[32];

    const int cnt  = *cnt_p;
    const int base = blockIdx.x * 32;
    if (base >= cnt) return;
    const int nt   = min(32, cnt - base);
    const int tid  = threadIdx.x;
    const int lane = tid & 63;
    const int wv   = tid >> 6;

    // ---- stage: einfo prefetch (8 independent loads), then unrolled row gathers ----
    {
        int4 ei[8];
        #pragma unroll
        for (int j = 0; j < 8; ++j) {
            int i = wv + j * 4;
            ei[j] = einfo[base + min(i, nt - 1)];
        }
        #pragma unroll
        for (int j = 0; j < 8; ++j) {
            int i = wv + j * 4;          // row in [0,32)
            int n = ei[j].x, e = ei[j].y, other = ei[j].z;
            float dtv = __int_as_float(ei[j].w);
            if (lane == 0) snode[i] = n;
            if (lane < 32) {
                float4 v = *(const float4*)&mem[(size_t)n * 128 + lane * 4];
                *(ushort4*)&XA[i * XASTR + lane * 4] = cvt4(v);
                float4 w = *(const float4*)&ef[(size_t)e * 128 + lane * 4];
                *(ushort4*)&XB[i * XBSTR + 128 + lane * 4] = cvt4(w);
            } else {
                int l = lane - 32;
                float4 v = *(const float4*)&mem[(size_t)other * 128 + l * 4];
                *(ushort4*)&XB[i * XBSTR + l * 4] = cvt4(v);
                float val = 0.0f;
                if (l < 16) {
                    float wt = fmaf(dtv, tw[l], tphi[l]);
                    val = (l == 0) ? wt : sinf(wt);
                }
                XB[i * XBSTR + 256 + l] = f2b(val);   // te(16) + zero(16)
            }
        }
    }
    __syncthreads();

    const int r16 = lane & 15;
    const int kb  = lane >> 4;

    // ---- layer 1: h1 = relu(x @ W1 + b1), M=32 N=128 K=416 ----
    f32x4 c1[2][2] = {};
    {
        const ushort* aA = &XA[r16 * XASTR + kb * 8];
        const ushort* aB = &XB[r16 * XBSTR + kb * 8];
        const ushort* bp = &W1T[(size_t)(wv * 32 + r16) * 416 + kb * 8];
        #pragma unroll
        for (int kt = 0; kt < 13; ++kt) {
            const ushort* ap  = (kt < 4) ? (aA + kt * 32) : (aB + (kt - 4) * 32);
            const int     ast = (kt < 4) ? XASTR : XBSTR;
            bf16x8 A0 = *(const bf16x8*)ap;
            bf16x8 A1 = *(const bf16x8*)(ap + 16 * ast);
            bf16x8 B0 = *(const bf16x8*)(bp + kt * 32);
            bf16x8 B1 = *(const bf16x8*)(bp + 16 * 416 + kt * 32);
            c1[0][0] = MFMA16(A0, B0, c1[0][0]);
            c1[0][1] = MFMA16(A0, B1, c1[0][1]);
            c1[1][0] = MFMA16(A1, B0, c1[1][0]);
            c1[1][1] = MFMA16(A1, B1, c1[1][1]);
        }
    }
    __syncthreads();   // all XB reads done; safe to overwrite with H

    #pragma unroll
    for (int ns = 0; ns < 2; ++ns) {
        int col = wv * 32 + ns * 16 + r16;
        float bb = b1[col];
        #pragma unroll
        for (int m = 0; m < 2; ++m)
            #pragma unroll
            for (int r = 0; r < 4; ++r)
                XB[(m * 16 + kb * 4 + r) * XBSTR + col] = f2b(fmaxf(c1[m][ns][r] + bb, 0.0f));
    }
    __syncthreads();

    // ---- layer 2: msg = h1 @ W2 + b2, K=128; write MSG to disjoint XB cols ----
    f32x4 c2[2][2] = {};
    {
        const ushort* aA = &XB[r16 * XBSTR + kb * 8];
        const ushort* bp = &W2T[(size_t)(wv * 32 + r16) * 128 + kb * 8];
        #pragma unroll
        for (int kt = 0; kt < 4; ++kt) {
            bf16x8 A0 = *(const bf16x8*)(aA + kt * 32);
            bf16x8 A1 = *(const bf16x8*)(aA + 16 * XBSTR + kt * 32);
            bf16x8 B0 = *(const bf16x8*)(bp + kt * 32);
            bf16x8 B1 = *(const bf16x8*)(bp + 16 * 128 + kt * 32);
            c2[0][0] = MFMA16(A0, B0, c2[0][0]);
            c2[0][1] = MFMA16(A0, B1, c2[0][1]);
            c2[1][0] = MFMA16(A1, B0, c2[1][0]);
            c2[1][1] = MFMA16(A1, B1, c2[1][1]);
        }
    }
    // MSG region (cols 136..263) is disjoint from H read region (0..127): no sync needed
    #pragma unroll
    for (int ns = 0; ns < 2; ++ns) {
        int col = wv * 32 + ns * 16 + r16;
        float bb = b2[col];
        #pragma unroll
        for (int m = 0; m < 2; ++m)
            #pragma unroll
            for (int r = 0; r < 4; ++r)
                XB[(m * 16 + kb * 4 + r) * XBSTR + 136 + col] = f2b(c2[m][ns][r] + bb);
    }
    __syncthreads();

    // ---- GRU ----
    f32x4 arz[2][4] = {};   // [m][gate*2+ns]
    f32x4 an_i[2][2] = {};
    f32x4 an_h[2][2] = {};
    {
        const ushort* am = &XB[r16 * XBSTR + 136 + kb * 8];
        const ushort* ah = &XA[r16 * XASTR + kb * 8];
        const size_t cb = (size_t)(wv * 32 + r16) * 128 + kb * 8;
        const ushort* bi = WI + cb;
        const ushort* bh = WH + cb;
        #pragma unroll
        for (int kt = 0; kt < 4; ++kt) {
            bf16x8 M0 = *(const bf16x8*)(am + kt * 32);
            bf16x8 M1 = *(const bf16x8*)(am + 16 * XBSTR + kt * 32);
            bf16x8 H0 = *(const bf16x8*)(ah + kt * 32);
            bf16x8 H1 = *(const bf16x8*)(ah + 16 * XASTR + kt * 32);
            #pragma unroll
            for (int g = 0; g < 2; ++g)
                #pragma unroll
                for (int ns = 0; ns < 2; ++ns) {
                    size_t off = (size_t)(g * 128 + ns * 16) * 128 + kt * 32;
                    bf16x8 Bi = *(const bf16x8*)(bi + off);
                    bf16x8 Bh = *(const bf16x8*)(bh + off);
                    arz[0][g * 2 + ns] = MFMA16(M0, Bi, arz[0][g * 2 + ns]);
                    arz[0][g * 2 + ns] = MFMA16(H0, Bh, arz[0][g * 2 + ns]);
                    arz[1][g * 2 + ns] = MFMA16(M1, Bi, arz[1][g * 2 + ns]);
                    arz[1][g * 2 + ns] = MFMA16(H1, Bh, arz[1][g * 2 + ns]);
                }
            #pragma unroll
            for (int ns = 0; ns < 2; ++ns) {
                size_t off = (size_t)(256 + ns * 16) * 128 + kt * 32;
                bf16x8 Bi = *(const bf16x8*)(bi + off);
                bf16x8 Bh = *(const bf16x8*)(bh + off);
                an_i[0][ns] = MFMA16(M0, Bi, an_i[0][ns]);
                an_i[1][ns] = MFMA16(M1, Bi, an_i[1][ns]);
                an_h[0][ns] = MFMA16(H0, Bh, an_h[0][ns]);
                an_h[1][ns] = MFMA16(H1, Bh, an_h[1][ns]);
            }
        }
    }
    __syncthreads();   // all LDS (Mh) reads done; XB reusable as f32 out-stage

    // ---- epilogue: gates + blend -> f32 stage in LDS ----
    float* __restrict__ XBf = (float*)XB;   // [32][OSTR]
    #pragma unroll
    for (int ns = 0; ns < 2; ++ns) {
        int col = wv * 32 + ns * 16 + r16;
        float brz0 = bih[col] + bhh[col];
        float brz1 = bih[128 + col] + bhh[128 + col];
        float bin  = bih[256 + col];
        float bhn  = bhh[256 + col];
        #pragma unroll
        for (int m = 0; m < 2; ++m) {
            #pragma unroll
            for (int r = 0; r < 4; ++r) {
                int row = m * 16 + kb * 4 + r;
                float rr = sigm(arz[m][0 + ns][r] + brz0);
                float zz = sigm(arz[m][2 + ns][r] + brz1);
                float nn = tanhf(an_i[m][ns][r] + bin + rr * (an_h[m][ns][r] + bhn));
                float hh = b2f(XA[row * XASTR + col]);
                XBf[row * OSTR + col] = (1.0f - zz) * nn + zz * hh;
            }
        }
    }
    __syncthreads();

    // ---- coalesced store: one wave writes a full 512 B row per instruction ----
    for (int j = wv; j < nt; j += 4) {
        float2 v = *(const float2*)&XBf[j * OSTR + lane * 2];
        *(float2*)&out[(size_t)snode[j] * 128 + lane * 2] = v;
    }
}

extern "C" void kernel_launch(void* const* d_in, const int* in_sizes, int n_in,
                              void* d_out, int out_size, void* d_ws, size_t ws_size,
                              hipStream_t stream) {
    const int*   src  = (const int*)d_in[0];
    const int*   dst  = (const int*)d_in[1];
    const float* ef   = (const float*)d_in[2];
    const float* ts   = (const float*)d_in[3];
    const float* mem  = (const float*)d_in[4];
    const float* lut  = (const float*)d_in[5];
    const float* tw   = (const float*)d_in[6];
    const float* tphi = (const float*)d_in[7];
    const float* W1   = (const float*)d_in[8];
    const float* b1   = (const float*)d_in[9];
    const float* W2   = (const float*)d_in[10];
    const float* b2   = (const float*)d_in[11];
    const float* Wih  = (const float*)d_in[12];
    const float* Whh  = (const float*)d_in[13];
    const float* bih  = (const float*)d_in[14];
    const float* bhh  = (const float*)d_in[15];
    float* out = (float*)d_out;

    char* ws = (char*)d_ws;
    int*    last_pos = (int*)ws;                                   // NN ints
    int4*   einfo    = (int4*)(ws + (size_t)NN * 4);               // NN int4 (16B-aligned)
    int*    cnt      = (int*)(ws + (size_t)NN * 4 + (size_t)NN * 16);
    ushort* W1T      = (ushort*)(ws + (size_t)NN * 4 + (size_t)NN * 16 + 16);
    ushort* W2T      = W1T + 128 * 416;
    ushort* WI       = W2T + 128 * 128;
    ushort* WH       = WI + 384 * 128;

    hipMemsetAsync(last_pos, 0xFF, (size_t)NN * sizeof(int), stream);  // -1
    hipMemsetAsync(cnt, 0, sizeof(int), stream);

    k_prepw<<<(128 * 416 + 128 * 128 + 2 * 384 * 128 + 255) / 256, 256, 0, stream>>>(
        W1, W2, Wih, Whh, W1T, W2T, WI, WH);
    k_scatter<<<(2 * NE + 255) / 256, 256, 0, stream>>>(src, dst, last_pos);
    k_compact<<<(NN + 255) / 256, 256, 0, stream>>>(last_pos, src, dst, ts, lut, einfo, cnt);
    k_copy_absent<<<(NN * 32 + 255) / 256, 256, 0, stream>>>(mem, last_pos, out);
    k_main<<<(NN + 31) / 32, 256, 0, stream>>>(einfo, cnt, ef, mem, tw, tphi,
                                               W1T, b1, W2T, b2, WI, WH, bih, bhh, out);
}